// Round 13
// baseline (81.862 us; speedup 1.0000x reference)
//
#include <hip/hip_runtime.h>
#include <hip/hip_bf16.h>

// Problem constants
#define Bsz 16
#define Lsz 512
#define Dsz 768
#define Tsz 12
#define Asz 64
#define N1  1536   // Tsz*Asz*2
#define Msz 8192   // Bsz*Lsz

typedef __bf16 bf16;
typedef bf16 bf16x2 __attribute__((ext_vector_type(2)));
typedef bf16 bf16x4 __attribute__((ext_vector_type(4)));
typedef bf16 bf16x8 __attribute__((ext_vector_type(8)));
typedef float f32x4 __attribute__((ext_vector_type(4)));
typedef unsigned long long u64;

// ---- prep (small): cvt_w | rope tables | mask bits ----
__global__ __launch_bounds__(256) void prep_kernel(
    const float* __restrict__ W, const int* __restrict__ mask,
    bf16* __restrict__ Wt, float* __restrict__ Tc, float* __restrict__ Ts,
    u64* __restrict__ Mbits) {
    int blk = blockIdx.x;
    if (blk < 576) {                        // cvt_w: N1*(Dsz/8) threads
        int tid = blk * 256 + threadIdx.x;
        int n  = tid % N1;
        int k0 = (tid / N1) * 8;
        bf16x8 o;
#pragma unroll
        for (int j = 0; j < 8; ++j) o[j] = (bf16)W[(size_t)(k0 + j) * N1 + n];
        *(bf16x8*)(Wt + (size_t)n * Dsz + k0) = o;
    } else if (blk < 704) {                 // rope tables: 512*64 threads
        int tid = (blk - 576) * 256 + threadIdx.x;
        int l = tid >> 6, a = tid & 63;
        float theta = expf(-0.28782313662425575f * (float)(a >> 1));  // 10000^(-(a>>1)/32)
        float pe = (float)l * theta;
        float s, c;
        sincosf(pe, &s, &c);
        Tc[tid] = c; Ts[tid] = s;
    } else {                                // mask bits: 16*512 threads
        int tid = (blk - 704) * 256 + threadIdx.x;
        u64 bal = __ballot(mask[tid] > 0);
        if ((tid & 63) == 0) Mbits[tid >> 6] = bal;
    }
}

__device__ __forceinline__ void rope_row(bf16* P, const float* tc, const float* ts) {
    float v[64];
#pragma unroll
    for (int c8 = 0; c8 < 8; ++c8) {
        bf16x8 x = *(const bf16x8*)(P + c8 * 8);
#pragma unroll
        for (int j = 0; j < 8; ++j) v[c8 * 8 + j] = (float)x[j];
    }
#pragma unroll
    for (int c8 = 0; c8 < 8; ++c8) {
        bf16x8 o;
#pragma unroll
        for (int j = 0; j < 8; ++j) {
            const int a  = c8 * 8 + j;
            const int a2 = (a < 32) ? (2 * a + 1) : (2 * (a - 32));
            const float sg = (a < 32) ? -1.f : 1.f;
            o[j] = (bf16)(v[a] * tc[a] + sg * v[a2] * ts[a]);
        }
        *(bf16x8*)(P + c8 * 8) = o;
    }
}

// ---- fused kernel: 192 compute blocks (proj from fp32 input via reg-staging
//      + rope + upper QK tiles) + 64 fill blocks (28 lower tiles x 3 z).
// Reg-staging (T14): issue 9 loads for t+1 early; MFMA on buf[cur] covers
// latency; cvt fp32->bf16; swizzled ds_write to buf[nxt]; lgkmcnt(0)+barrier.
// Swizzle invariant: LDS 16B-slot s of row r holds global chunk s^((r>>1)&3);
// frag reads use koff = (hi^((l15>>1)&3))*16.
#define SBUF 40960   // A 32768 + W 8192 per staging buffer (2 buffers, aliased)
__global__ __launch_bounds__(512) void fused_kernel(
    const float* __restrict__ inA, const bf16* __restrict__ Wt,
    const float* __restrict__ bias,
    const float* __restrict__ Tc, const float* __restrict__ Ts,
    const u64* __restrict__ Mbits, float* __restrict__ out) {
    __shared__ char smem[147456];
    const int bid = blockIdx.x;
    const int tid = threadIdx.x;

    if (bid >= 192) {
        // -------- fill role: all 28 below-diagonal tiles of 3 z each --------
        const int w = bid - 192;
        const f32x4 f = {-1e12f, -1e12f, -1e12f, -1e12f};
        const u64 itlo = 0x6555554444333221ull, ithi = 0x0000777777766666ull;
        const u64 jtlo = 0x0432103210210100ull, jthi = 0x0000654321054321ull;
        for (int zz = 0; zz < 3; ++zz) {
            float* ob = out + (size_t)(w * 3 + zz) * Lsz * Lsz;
#pragma unroll
            for (int p = 0; p < 28; ++p) {
                const int it = (int)(((p < 16) ? (itlo >> (4 * p)) : (ithi >> (4 * (p - 16)))) & 15);
                const int jt = (int)(((p < 16) ? (jtlo >> (4 * p)) : (jthi >> (4 * (p - 16)))) & 15);
#pragma unroll
                for (int rep = 0; rep < 2; ++rep) {
                    const int idx = rep * 512 + tid;
                    const int r = idx >> 4, c = (idx & 15) << 2;
                    *(f32x4*)(ob + (size_t)(it * 64 + r) * Lsz + jt * 64 + c) = f;
                }
            }
        }
        return;
    }

    // ---------------- compute role ----------------
    bf16* Xq = (bf16*)smem;                  // [512][72]
    bf16* Xk = (bf16*)(smem + 73728);        // [512][72]

    const int z  = (bid & 7) * 24 + (bid >> 3);   // XCD-chunked
    const int b  = z / Tsz, th = z % Tsz;

    const int wave = tid >> 6, lane = tid & 63;
    const int l15 = lane & 15, hi = lane >> 4;
    const int wm = wave >> 1, wn = wave & 1;

    const float* Af = inA + (size_t)b * Lsz * Dsz;     // fp32 A panel
    const bf16*  Wb = Wt + (size_t)th * 128 * Dsz;
    float* ob = out + (size_t)z * Lsz * Lsz;
    const int lq = lane >> 2;                           // row-within-16 group
    const int g8  = (lane & 3) * 8;                     // natural global chunk (elems)
    const int sw8 = ((lane & 3) ^ ((lane >> 3) & 3)) * 8;  // swizzled LDS slot (elems)
    const int rw = wave * 16 + lq;                      // W row this thread stages
    const int koff = (hi ^ ((l15 >> 1) & 3)) * 16;      // swizzled frag read (bytes)

    // ---------- phase 1: projection 512x128 = A(fp32) @ W_head^T ----------
    f32x4 acc[8][4] = {};
    float4 ar[8];          // in-flight A fp32 (4 rows x 8 elems)
    bf16x8 wreg;           // in-flight W row chunk

#define ISSUE(kk)                                                               \
    do {                                                                        \
        _Pragma("unroll")                                                       \
        for (int i = 0; i < 4; ++i) {                                           \
            const float* src = Af + (size_t)(wave * 64 + i * 16 + lq) * Dsz + (kk) + g8; \
            ar[2 * i]     = *(const float4*)(src);                              \
            ar[2 * i + 1] = *(const float4*)(src + 4);                          \
        }                                                                       \
        wreg = *(const bf16x8*)(Wb + (size_t)rw * Dsz + (kk) + g8);             \
    } while (0)

#define WRITEBUF(buf)                                                           \
    do {                                                                        \
        bf16* As = (bf16*)(smem + (buf) * SBUF);                                \
        bf16* Ws = (bf16*)(smem + (buf) * SBUF + 32768);                        \
        _Pragma("unroll")                                                       \
        for (int i = 0; i < 4; ++i) {                                           \
            bf16x8 o;                                                           \
            o[0] = (bf16)ar[2 * i].x;     o[1] = (bf16)ar[2 * i].y;             \
            o[2] = (bf16)ar[2 * i].z;     o[3] = (bf16)ar[2 * i].w;             \
            o[4] = (bf16)ar[2 * i + 1].x; o[5] = (bf16)ar[2 * i + 1].y;         \
            o[6] = (bf16)ar[2 * i + 1].z; o[7] = (bf16)ar[2 * i + 1].w;         \
            *(bf16x8*)(As + (wave * 64 + i * 16 + lq) * 32 + sw8) = o;          \
        }                                                                       \
        *(bf16x8*)(Ws + rw * 32 + sw8) = wreg;                                  \
    } while (0)

    ISSUE(0);
    WRITEBUF(0);
    __syncthreads();

    int cur = 0;
    for (int t = 0; t < 24; ++t) {
        if (t + 1 < 24) ISSUE((t + 1) * 32);   // loads in flight across MFMA

        const char* As = smem + cur * SBUF;
        const char* Ws = smem + cur * SBUF + 32768;
        bf16x8 af[8], bw[4];
#pragma unroll
        for (int mf = 0; mf < 8; ++mf)
            af[mf] = *(const bf16x8*)(As + (wm * 128 + mf * 16 + l15) * 64 + koff);
#pragma unroll
        for (int nf = 0; nf < 4; ++nf)
            bw[nf] = *(const bf16x8*)(Ws + (wn * 64 + nf * 16 + l15) * 64 + koff);
#pragma unroll
        for (int mf = 0; mf < 8; ++mf)
#pragma unroll
            for (int nf = 0; nf < 4; ++nf)
                acc[mf][nf] = __builtin_amdgcn_mfma_f32_16x16x32_bf16(af[mf], bw[nf], acc[mf][nf], 0, 0, 0);

        if (t + 1 < 24) {
            WRITEBUF(cur ^ 1);                 // compiler inserts vmcnt before ar use
            asm volatile("s_waitcnt lgkmcnt(0)" ::: "memory");
            __builtin_amdgcn_s_barrier();
        }
        cur ^= 1;
    }
#undef ISSUE
#undef WRITEBUF
    __syncthreads();    // staging dead; smem becomes planes

    // ---------- phase 2: acc (+bias) -> q/k planes ----------
    // C/D: col=wn*64+nf*16+l15, row=wm*128+mf*16+hi*4+r. col c: even->q, odd->k.
    {
        const int r0 = hi * 4;
#pragma unroll
        for (int nf = 0; nf < 4; ++nf) {
            const int c = wn * 64 + nf * 16 + l15;
            const float bv = bias[th * 128 + c];
            bf16* P = (c & 1) ? Xk : Xq;
            const int a = c >> 1;
#pragma unroll
            for (int mf = 0; mf < 8; ++mf) {
                const int rwp = wm * 128 + mf * 16 + r0;
#pragma unroll
                for (int r = 0; r < 4; ++r)
                    P[(rwp + r) * 72 + a] = (bf16)(acc[mf][nf][r] + bv);
            }
        }
    }
    __syncthreads();

    // ---------- phase 3: rope in place (thread = row l) ----------
    rope_row(Xq + tid * 72, Tc + tid * 64, Ts + tid * 64);
    rope_row(Xk + tid * 72, Tc + tid * 64, Ts + tid * 64);
    __syncthreads();

    // ---------- phase 4: QK^T + mask, upper tiles only ----------
    const u64* mb = Mbits + b * 8;
#pragma unroll
    for (int s = 0; s < 8; ++s) {
        const int it = s, jt = (wave - s) & 7;    // (it+jt)%8==wave
        if (jt < it) continue;
        const int i0 = it * 64, j0 = jt * 64;
        const u64 jb = mb[jt], ib = mb[it];
        bf16x8 k0[4], k1[4];
#pragma unroll
        for (int ct = 0; ct < 4; ++ct) {
            const int jr = j0 + ct * 16 + l15;
            k0[ct] = *(const bf16x8*)(Xk + jr * 72 + hi * 8);
            k1[ct] = *(const bf16x8*)(Xk + jr * 72 + 32 + hi * 8);
        }
#pragma unroll
        for (int is = 0; is < 4; ++is) {
            const int ir = i0 + is * 16 + l15;
            bf16x8 q0 = *(const bf16x8*)(Xq + ir * 72 + hi * 8);
            bf16x8 q1 = *(const bf16x8*)(Xq + ir * 72 + 32 + hi * 8);
            f32x4 a4[4] = {};
#pragma unroll
            for (int ct = 0; ct < 4; ++ct) {
                a4[ct] = __builtin_amdgcn_mfma_f32_16x16x32_bf16(k0[ct], q0, a4[ct], 0, 0, 0);
                a4[ct] = __builtin_amdgcn_mfma_f32_16x16x32_bf16(k1[ct], q1, a4[ct], 0, 0, 0);
            }
            const bool mi = (ib >> (is * 16 + l15)) & 1;
#pragma unroll
            for (int ct = 0; ct < 4; ++ct) {
                const int jbase = ct * 16 + hi * 4;
                f32x4 vv;
#pragma unroll
                for (int r = 0; r < 4; ++r) {
                    const int j = j0 + jbase + r;
                    const bool keep = mi && ((jb >> (jbase + r)) & 1) && (ir <= j);
                    vv[r] = keep ? a4[ct][r] : -1e12f;
                }
                *(f32x4*)(ob + (size_t)ir * Lsz + j0 + jbase) = vv;
            }
        }
    }
}

extern "C" void kernel_launch(void* const* d_in, const int* in_sizes, int n_in,
                              void* d_out, int out_size, void* d_ws, size_t ws_size,
                              hipStream_t stream) {
    const float* in_f  = (const float*)d_in[0];
    const int*   amask = (const int*)d_in[1];
    const float* W     = (const float*)d_in[2];
    const float* bias  = (const float*)d_in[3];
    float* out = (float*)d_out;

    char* ws = (char*)d_ws;
    bf16*  Wt    = (bf16*)ws;                                //  2,359,296 B
    float* Tc    = (float*)(ws + 2359296);                   //    131,072 B
    float* Ts    = (float*)(ws + 2490368);                   //    131,072 B
    u64*   Mbits = (u64*)(ws + 2621440);                     //      1,024 B

    prep_kernel<<<736, 256, 0, stream>>>(W, amask, Wt, Tc, Ts, Mbits);
    fused_kernel<<<256, 512, 0, stream>>>(in_f, Wt, bias, Tc, Ts, Mbits, out);
}